// Round 10
// baseline (4949.188 us; speedup 1.0000x reference)
//
#include <hip/hip_runtime.h>

// Net_46076409152296: spiking net fwd (RLeaky + Leaky). B=1024,T=32,D=2312,H=512,O=10.
// d_out is FP32 (decoded round 9: 4.609375 = two of our bf16 u16s packed into one
// fp32 slot; kernels have executed since round 0 — failures were spike flips).
// v10: all dot products accumulate in FLOAT64 (exact products, ~exact sums ->
// correctly-rounded fp32 dot), state updates in fp32 with non-fused rounding in
// the reference's association order. Single fused kernel; block owns 2 batch
// rows, runs all T=32 steps. cur1 kept in LDS (no runtime-indexed reg arrays).

__global__ __launch_bounds__(256) void Net_46076409152296_kernel(
    const float* __restrict__ x, const float* __restrict__ W1,
    const float* __restrict__ b1, const float* __restrict__ Wr,
    const float* __restrict__ br, const float* __restrict__ W2,
    const float* __restrict__ b2, float* __restrict__ out) {
  const int B = 1024, T = 32, D = 2312, H = 512, O = 10;
  // Rr=2 rows/block, TC=8 steps/chunk, 4 chunks.

  __shared__ double xs[2][8][8];     // staged x slab (f64), 1 KB
  __shared__ double spkd[2][512];    // current spikes as f64 (0/1 exact), 8 KB
  __shared__ float  cur1[2][8][512]; // fc1 results for the chunk, 32 KB

  const int j = threadIdx.x;         // 0..255; owns hidden units j and j+256
  const int h0 = j, h1 = j + 256;
  const int b0 = blockIdx.x * 2;

  float m1a[2], m1b[2];
  m1a[0] = m1a[1] = m1b[0] = m1b[1] = 0.0f;
  float m2 = 0.0f;

  spkd[0][h0] = 0.0; spkd[0][h1] = 0.0;
  spkd[1][h0] = 0.0; spkd[1][h1] = 0.0;
  __syncthreads();

  const float b1a = b1[h0], b1b = b1[h1];
  const float bra = br[h0], brb = br[h1];
  const float* __restrict__ w1a = W1 + (size_t)h0 * D;
  const float* __restrict__ w1b = W1 + (size_t)h1 * D;
  const float* __restrict__ wra = Wr + (size_t)h0 * H;
  const float* __restrict__ wrb = Wr + (size_t)h1 * H;

  // x staging role (threads 0..127): (sr, stt, skk) with 2*8*8 = 128 slots
  const int sr = j >> 6, stt = (j >> 3) & 7, skk = j & 7;
  const float* __restrict__ xp =
      (j < 128) ? (x + ((size_t)(b0 + sr) * T + stt) * D + skk) : nullptr;

  for (int c = 0; c < 4; ++c) {
    const int tbase = c * 8;

    // ---- fc1: acc[m] = dot_f64(x[b0+(m>>3), tbase+(m&7), :], W1[h,:]) ----
    double acc0[16], acc1[16];
#pragma unroll
    for (int m = 0; m < 16; ++m) { acc0[m] = 0.0; acc1[m] = 0.0; }

    const float* __restrict__ xpc = xp ? (xp + (size_t)tbase * D) : nullptr;
    for (int k0 = 0; k0 < D; k0 += 8) {   // D = 289 * 8
      __syncthreads();                    // previous slab consumed
      if (j < 128) xs[sr][stt][skk] = (double)xpc[k0];
      __syncthreads();                    // new slab visible
#pragma unroll
      for (int kh = 0; kh < 8; kh += 4) {
        const float4 wa4 = *(const float4*)(w1a + k0 + kh);
        const float4 wb4 = *(const float4*)(w1b + k0 + kh);
        const double wa0 = wa4.x, wa1 = wa4.y, wa2 = wa4.z, wa3 = wa4.w;
        const double wb0 = wb4.x, wb1 = wb4.y, wb2 = wb4.z, wb3 = wb4.w;
#pragma unroll
        for (int m = 0; m < 16; ++m) {
          const double a0 = xs[m >> 3][m & 7][kh + 0];
          const double a1 = xs[m >> 3][m & 7][kh + 1];
          const double a2 = xs[m >> 3][m & 7][kh + 2];
          const double a3 = xs[m >> 3][m & 7][kh + 3];
          acc0[m] = fma(a3, wa3, fma(a2, wa2, fma(a1, wa1, fma(a0, wa0, acc0[m]))));
          acc1[m] = fma(a3, wb3, fma(a2, wb2, fma(a1, wb1, fma(a0, wb0, acc1[m]))));
        }
      }
    }
    __syncthreads();
#pragma unroll
    for (int m = 0; m < 16; ++m) {
      cur1[m >> 3][m & 7][h0] = __fadd_rn((float)acc0[m], b1a);
      cur1[m >> 3][m & 7][h1] = __fadd_rn((float)acc1[m], b1b);
    }
    __syncthreads();

    // ---- scan: 8 recurrent steps ----
    for (int tt = 0; tt < 8; ++tt) {
      double r0d[2] = {0.0, 0.0}, r1d[2] = {0.0, 0.0};
      for (int k = 0; k < H; k += 4) {
        const float4 wa4 = *(const float4*)(wra + k);
        const float4 wb4 = *(const float4*)(wrb + k);
        const double wa0 = wa4.x, wa1 = wa4.y, wa2 = wa4.z, wa3 = wa4.w;
        const double wb0 = wb4.x, wb1 = wb4.y, wb2 = wb4.z, wb3 = wb4.w;
#pragma unroll
        for (int r = 0; r < 2; ++r) {
          const double s0 = spkd[r][k + 0], s1 = spkd[r][k + 1];
          const double s2 = spkd[r][k + 2], s3 = spkd[r][k + 3];
          r0d[r] = fma(s3, wa3, fma(s2, wa2, fma(s1, wa1, fma(s0, wa0, r0d[r]))));
          r1d[r] = fma(s3, wb3, fma(s2, wb2, fma(s1, wb1, fma(s0, wb0, r1d[r]))));
        }
      }
      __syncthreads();  // all reads of old spikes complete
#pragma unroll
      for (int r = 0; r < 2; ++r) {
        // mem1 = ((0.99*mem1 + cur1) + (rec + br)) - reset   (non-fused fp32)
        float mo = m1a[r];
        float rst = (mo - 1.0f > 0.0f) ? 1.0f : 0.0f;
        float mn = __fsub_rn(
            __fadd_rn(__fadd_rn(__fmul_rn(0.99f, mo), cur1[r][tt][h0]),
                      __fadd_rn((float)r0d[r], bra)),
            rst);
        m1a[r] = mn;
        spkd[r][h0] = (mn - 1.0f > 0.0f) ? 1.0 : 0.0;

        mo = m1b[r];
        rst = (mo - 1.0f > 0.0f) ? 1.0f : 0.0f;
        mn = __fsub_rn(
            __fadd_rn(__fadd_rn(__fmul_rn(0.99f, mo), cur1[r][tt][h1]),
                      __fadd_rn((float)r1d[r], brb)),
            rst);
        m1b[r] = mn;
        spkd[r][h1] = (mn - 1.0f > 0.0f) ? 1.0 : 0.0;
      }
      __syncthreads();  // new spikes visible
      // fc2 + mem2 + outputs: threads 0..19 (r2 = j/10, o2 = j%10). Their spkd
      // reads finish before the next step's pre-write barrier -> race-free.
      if (j < 20) {
        const int r2 = j / 10;
        const int o2 = j - r2 * 10;
        const float* __restrict__ w2r = W2 + (size_t)o2 * H;
        double a2d = 0.0;
        for (int k = 0; k < H; k += 4) {
          const float4 w4 = *(const float4*)(w2r + k);
          a2d = fma(spkd[r2][k + 3], (double)w4.w,
                fma(spkd[r2][k + 2], (double)w4.z,
                fma(spkd[r2][k + 1], (double)w4.y,
                fma(spkd[r2][k + 0], (double)w4.x, a2d))));
        }
        const float cur2 = __fadd_rn((float)a2d, b2[o2]);
        const float rst2 = (m2 - 1.0f > 0.0f) ? 1.0f : 0.0f;
        const float mn2 =
            __fsub_rn(__fadd_rn(__fmul_rn(0.99f, m2), cur2), rst2);
        m2 = mn2;
        const int t = tbase + tt;
        const size_t oidx = ((size_t)t * B + (b0 + r2)) * O + o2;
        out[oidx] = (mn2 - 1.0f > 0.0f) ? 1.0f : 0.0f;   // spk2
        out[(size_t)T * B * O + oidx] = mn2;             // mem2
      }
    }
  }
}

extern "C" void kernel_launch(void* const* d_in, const int* in_sizes, int n_in,
                              void* d_out, int out_size, void* d_ws, size_t ws_size,
                              hipStream_t stream) {
  const float* x  = (const float*)d_in[0];
  const float* W1 = (const float*)d_in[1];
  const float* b1 = (const float*)d_in[2];
  const float* Wr = (const float*)d_in[3];
  const float* br = (const float*)d_in[4];
  const float* W2 = (const float*)d_in[5];
  const float* b2 = (const float*)d_in[6];
  float* out = (float*)d_out;  // FP32 output buffer
  (void)in_sizes; (void)n_in; (void)out_size; (void)d_ws; (void)ws_size;

  Net_46076409152296_kernel<<<512, 256, 0, stream>>>(
      x, W1, b1, Wr, br, W2, b2, out);
}